// Round 1
// baseline (132.254 us; speedup 1.0000x reference)
//
#include <hip/hip_runtime.h>
#include <math.h>

// RPN anchor target layer (py-faster-rcnn convention), MI355X.
// Outputs concatenated: anchors (K*4) | bbox_targets (K*4) | labels (K), fp32.
// K = r*c*15 (r=c=100 for the fixed setup), G = #gt boxes (100).
//
// Labels must be bit-exact vs the numpy/jax reference (threshold ~0.02), so all
// IoU / transform arithmetic uses non-contractible _rn intrinsics in the exact
// reference op order. Anchor coordinates themselves are exactly representable
// (multiples of 0.5 below 2^12), so the geometry is exact by construction.

#define NUM_A 15
#define NUM_FG 128      // int(0.5 * 256)
#define RPN_BATCH 256
#define SEGS 40         // per-gt argmax split factor

__device__ __forceinline__ void base_anchor(int a, float& bx1, float& by1,
                                            float& bx2, float& by2) {
    // generate_anchors(base=16, ratios={0.5,1,2}, scales={1,2,4,8,16}):
    // ratio 0.5 -> (w,h)=(23,12); 1.0 -> (16,16); 2.0 -> (11,22). Verified vs
    // jnp.round (half-to-even): round(sqrt(512))=23, round(11.5)=12, etc.
    const float RW[3] = {23.f, 16.f, 11.f};
    const float RH[3] = {12.f, 16.f, 22.f};
    int i = a / 5;
    int j = a - i * 5;
    float sc = (float)(1 << j);          // scales 1,2,4,8,16
    float w = RW[i] * sc;
    float h = RH[i] * sc;
    bx1 = 7.5f - 0.5f * (w - 1.f);       // exact (.0/.5 values)
    by1 = 7.5f - 0.5f * (h - 1.f);
    bx2 = 7.5f + 0.5f * (w - 1.f);
    by2 = 7.5f + 0.5f * (h - 1.f);
}

__device__ __forceinline__ void anchor_coords(int k, int c, float& x1, float& y1,
                                              float& x2, float& y2) {
    int a = k % NUM_A;
    int p = k / NUM_A;
    int xi = p % c;
    int yi = p / c;
    float bx1, by1, bx2, by2;
    base_anchor(a, bx1, by1, bx2, by2);
    float sx = (float)xi * 16.f;
    float sy = (float)yi * 16.f;
    x1 = sx + bx1;  y1 = sy + by1;       // exact adds
    x2 = sx + bx2;  y2 = sy + by2;
}

// IoU in exact reference order: iw/ih -> inter -> (area_a + area_b) - inter -> div.
__device__ __forceinline__ float iou_pair(float cx1, float cy1, float cx2, float cy2,
                                          float area_a,
                                          float gx1, float gy1, float gx2, float gy2) {
    float gw = __fadd_rn(__fsub_rn(gx2, gx1), 1.f);
    float gh = __fadd_rn(__fsub_rn(gy2, gy1), 1.f);
    float area_b = __fmul_rn(gw, gh);
    float iw = __fadd_rn(__fsub_rn(fminf(cx2, gx2), fmaxf(cx1, gx1)), 1.f);
    float ih = __fadd_rn(__fsub_rn(fminf(cy2, gy2), fmaxf(cy1, gy1)), 1.f);
    float inter = __fmul_rn(fmaxf(iw, 0.f), fmaxf(ih, 0.f));
    float denom = __fsub_rn(__fadd_rn(area_a, area_b), inter);
    return __fdiv_rn(inter, denom);
}

// ---------------- kernel 1: per-(gt, segment) partial argmax over anchors -----------
__global__ void k_gt_partial(const float* __restrict__ gt, const float* __restrict__ meta,
                             float* __restrict__ pval, int* __restrict__ pidx,
                             int K, int c, int seg_len) {
    int s = blockIdx.x;          // segment
    int g = blockIdx.y;          // gt index
    float gx1 = gt[g * 4 + 0], gy1 = gt[g * 4 + 1];
    float gx2 = gt[g * 4 + 2], gy2 = gt[g * 4 + 3];
    float h = meta[0], w = meta[1];
    float wm1 = __fsub_rn(w, 1.f), hm1 = __fsub_rn(h, 1.f);

    int k0 = s * seg_len;
    int k1 = k0 + seg_len; if (k1 > K) k1 = K;

    float bestv = -3.f;          // below the -1 "outside" sentinel
    int   besti = 0x7fffffff;
    for (int k = k0 + threadIdx.x; k < k1; k += blockDim.x) {
        float x1, y1, x2, y2;
        anchor_coords(k, c, x1, y1, x2, y2);
        bool inside = (x1 >= 0.f) && (y1 >= 0.f) && (x2 < w) && (y2 < h);
        float v = -1.f;          // masked overlap for outside anchors
        if (inside) {
            float cx1 = fminf(fmaxf(x1, 0.f), wm1);
            float cy1 = fminf(fmaxf(y1, 0.f), hm1);
            float cx2 = fminf(fmaxf(x2, 0.f), wm1);
            float cy2 = fminf(fmaxf(y2, 0.f), hm1);
            float area_a = __fmul_rn(__fadd_rn(__fsub_rn(cx2, cx1), 1.f),
                                     __fadd_rn(__fsub_rn(cy2, cy1), 1.f));
            v = iou_pair(cx1, cy1, cx2, cy2, area_a, gx1, gy1, gx2, gy2);
        }
        // strictly-greater keeps the FIRST (lowest-k) max within this thread
        if (v > bestv) { bestv = v; besti = k; }
    }

    __shared__ float sv[256];
    __shared__ int   si[256];
    sv[threadIdx.x] = bestv; si[threadIdx.x] = besti;
    __syncthreads();
    for (int st = 128; st > 0; st >>= 1) {
        if (threadIdx.x < st) {
            float ov = sv[threadIdx.x + st]; int oi = si[threadIdx.x + st];
            if (ov > sv[threadIdx.x] ||
                (ov == sv[threadIdx.x] && oi < si[threadIdx.x])) {
                sv[threadIdx.x] = ov; si[threadIdx.x] = oi;
            }
        }
        __syncthreads();
    }
    if (threadIdx.x == 0) {
        pval[g * SEGS + s] = sv[0];
        pidx[g * SEGS + s] = si[0];
    }
}

// ---------------- kernel 2: reduce segments -> gt_best[g] ---------------------------
__global__ void k_gt_reduce(const float* __restrict__ pval, const int* __restrict__ pidx,
                            int* __restrict__ gt_best) {
    int g = blockIdx.x;
    int t = threadIdx.x;         // 64 threads
    float v = -3.f; int i = 0x7fffffff;
    if (t < SEGS) { v = pval[g * SEGS + t]; i = pidx[g * SEGS + t]; }
    for (int off = 32; off > 0; off >>= 1) {
        float ov = __shfl_down(v, off);
        int   oi = __shfl_down(i, off);
        if (ov > v || (ov == v && oi < i)) { v = ov; i = oi; }
    }
    if (t == 0) gt_best[g] = i;
}

// ---------------- kernel 3: per-anchor main pass ------------------------------------
__global__ void k_anchor(const float* __restrict__ gt, const float* __restrict__ meta,
                         const int* __restrict__ gt_best,
                         float* __restrict__ out_anch, float* __restrict__ out_bb,
                         float* __restrict__ out_lab,
                         int* __restrict__ posc, int* __restrict__ negc,
                         int K, int c, int G) {
    __shared__ float s_gt[1024];   // up to 256 gt boxes
    __shared__ int   s_best[256];
    for (int i = threadIdx.x; i < G * 4; i += blockDim.x) s_gt[i] = gt[i];
    for (int i = threadIdx.x; i < G; i += blockDim.x)     s_best[i] = gt_best[i];
    __syncthreads();

    int k = blockIdx.x * blockDim.x + threadIdx.x;
    bool valid = (k < K);
    float labf = -1.f;
    if (valid) {
        float x1, y1, x2, y2;
        anchor_coords(k, c, x1, y1, x2, y2);
        ((float4*)out_anch)[k] = make_float4(x1, y1, x2, y2);

        float h = meta[0], w = meta[1];
        bool inside = (x1 >= 0.f) && (y1 >= 0.f) && (x2 < w) && (y2 < h);

        float wm1 = __fsub_rn(w, 1.f), hm1 = __fsub_rn(h, 1.f);
        float cx1 = fminf(fmaxf(x1, 0.f), wm1);
        float cy1 = fminf(fmaxf(y1, 0.f), hm1);
        float cx2 = fminf(fmaxf(x2, 0.f), wm1);
        float cy2 = fminf(fmaxf(y2, 0.f), hm1);
        float area_a = __fmul_rn(__fadd_rn(__fsub_rn(cx2, cx1), 1.f),
                                 __fadd_rn(__fsub_rn(cy2, cy1), 1.f));

        float t0 = 0.f, t1 = 0.f, t2 = 0.f, t3 = 0.f;
        if (inside) {
            float maxv = -2.f; int arg = 0;
            for (int g = 0; g < G; ++g) {
                float v = iou_pair(cx1, cy1, cx2, cy2, area_a,
                                   s_gt[g * 4 + 0], s_gt[g * 4 + 1],
                                   s_gt[g * 4 + 2], s_gt[g * 4 + 3]);
                if (v > maxv) { maxv = v; arg = g; }   // first-index argmax
            }
            bool is_gt_best = false;
            for (int g = 0; g < G; ++g) is_gt_best = is_gt_best || (s_best[g] == k);
            // order in reference: <0.3 -> 0; gt_best scatter -> 1; >=0.7 -> 1
            labf = (is_gt_best || maxv >= 0.7f) ? 1.f : (maxv < 0.3f ? 0.f : -1.f);

            float gx1 = s_gt[arg * 4 + 0], gy1 = s_gt[arg * 4 + 1];
            float gx2 = s_gt[arg * 4 + 2], gy2 = s_gt[arg * 4 + 3];
            float ew  = __fadd_rn(__fsub_rn(cx2, cx1), 1.f);
            float eh  = __fadd_rn(__fsub_rn(cy2, cy1), 1.f);
            float ecx = __fadd_rn(cx1, __fmul_rn(0.5f, ew));
            float ecy = __fadd_rn(cy1, __fmul_rn(0.5f, eh));
            float gw  = __fadd_rn(__fsub_rn(gx2, gx1), 1.f);
            float gh  = __fadd_rn(__fsub_rn(gy2, gy1), 1.f);
            float gcx = __fadd_rn(gx1, __fmul_rn(0.5f, gw));
            float gcy = __fadd_rn(gy1, __fmul_rn(0.5f, gh));
            t0 = __fdiv_rn(__fsub_rn(gcx, ecx), ew);
            t1 = __fdiv_rn(__fsub_rn(gcy, ecy), eh);
            t2 = logf(__fdiv_rn(gw, ew));
            t3 = logf(__fdiv_rn(gh, eh));
        }
        ((float4*)out_bb)[k] = make_float4(t0, t1, t2, t3);
        out_lab[k] = labf;
    }

    // per-block pos/neg counts for the global cumsum
    bool pos = valid && (labf == 1.f);
    bool neg = valid && (labf == 0.f);
    unsigned long long bp = __ballot(pos ? 1 : 0);
    unsigned long long bn = __ballot(neg ? 1 : 0);
    __shared__ int swp[4], swn[4];
    int lane = threadIdx.x & 63, wid = threadIdx.x >> 6;
    if (lane == 0) { swp[wid] = __popcll(bp); swn[wid] = __popcll(bn); }
    __syncthreads();
    if (threadIdx.x == 0) {
        posc[blockIdx.x] = swp[0] + swp[1] + swp[2] + swp[3];
        negc[blockIdx.x] = swn[0] + swn[1] + swn[2] + swn[3];
    }
}

// ---------------- kernel 4: scan block counts (in-place -> exclusive offsets) -------
__global__ void k_scan(int* __restrict__ posc, int* __restrict__ negc,
                       int* __restrict__ numbg, int NB) {
    __shared__ int sp[1024], sn[1024];
    int t = threadIdx.x;
    int carry_p = 0, carry_n = 0;
    for (int base = 0; base < NB; base += 1024) {
        int idx = base + t;
        int op = (idx < NB) ? posc[idx] : 0;
        int on = (idx < NB) ? negc[idx] : 0;
        sp[t] = op; sn[t] = on;
        __syncthreads();
        int vp = sp[t], vn = sn[t];
        for (int off = 1; off < 1024; off <<= 1) {
            int ap = 0, an = 0;
            if (t >= off) { ap = sp[t - off]; an = sn[t - off]; }
            __syncthreads();
            vp += ap; vn += an;
            sp[t] = vp; sn[t] = vn;
            __syncthreads();
        }
        if (idx < NB) { posc[idx] = carry_p + vp - op; negc[idx] = carry_n + vn - on; }
        carry_p += sp[1023];
        carry_n += sn[1023];
        __syncthreads();
    }
    if (t == 0) {
        int total_pos = carry_p;
        int np = total_pos > NUM_FG ? NUM_FG : total_pos;
        numbg[0] = RPN_BATCH - np;
    }
}

// ---------------- kernel 5: apply pos/neg rank caps ---------------------------------
__global__ void k_apply(float* __restrict__ lab, const int* __restrict__ posoff,
                        const int* __restrict__ negoff, const int* __restrict__ numbg,
                        int K) {
    int k = blockIdx.x * blockDim.x + threadIdx.x;
    bool valid = (k < K);
    float lv = -1.f;
    if (valid) lv = lab[k];
    bool pos = valid && (lv == 1.f);
    bool neg = valid && (lv == 0.f);
    unsigned long long bp = __ballot(pos ? 1 : 0);
    unsigned long long bn = __ballot(neg ? 1 : 0);
    int lane = threadIdx.x & 63, wid = threadIdx.x >> 6;
    unsigned long long lm = (1ULL << lane) - 1ULL;
    int pw = __popcll(bp & lm);
    int nw = __popcll(bn & lm);
    __shared__ int swp[4], swn[4];
    if (lane == 0) { swp[wid] = __popcll(bp); swn[wid] = __popcll(bn); }
    __syncthreads();
    int poff = 0, noff = 0;
    for (int i = 0; i < wid; ++i) { poff += swp[i]; noff += swn[i]; }
    int prank = posoff[blockIdx.x] + poff + pw + 1;   // inclusive cumsum rank
    int nrank = negoff[blockIdx.x] + noff + nw + 1;
    int nb = numbg[0];
    if (pos && prank > NUM_FG) lab[k] = -1.f;
    if (neg && nrank > nb)     lab[k] = -1.f;
}

extern "C" void kernel_launch(void* const* d_in, const int* in_sizes, int n_in,
                              void* d_out, int out_size, void* d_ws, size_t ws_size,
                              hipStream_t stream) {
    const float* gt   = (const float*)d_in[0];   // (1,G,4)
    const float* meta = (const float*)d_in[1];   // (1,3): h, w, scale
    // d_in[2] (scores) only contributes its shape: r*c*A elements
    int G  = in_sizes[0] / 4;
    int rc = in_sizes[2] / NUM_A;
    int c = 1;
    while ((long long)(c + 1) * (c + 1) <= (long long)rc) ++c;   // square feature map
    int K  = rc * NUM_A;
    int NB = (K + 255) / 256;
    int seg_len = (K + SEGS - 1) / SEGS;

    float* out      = (float*)d_out;
    float* out_anch = out;                       // K*4
    float* out_bb   = out + (size_t)4 * K;       // K*4
    float* out_lab  = out + (size_t)8 * K;       // K

    int* wsi     = (int*)d_ws;
    int* gt_best = wsi;                          // 256 slots
    int* posc    = wsi + 256;                    // NB
    int* negc    = posc + NB;                    // NB
    int* numbg   = negc + NB;                    // 1
    int* pidx    = numbg + 1;                    // G*SEGS
    float* pval  = (float*)(pidx + (size_t)G * SEGS);  // G*SEGS

    hipLaunchKernelGGL(k_gt_partial, dim3(SEGS, G), dim3(256), 0, stream,
                       gt, meta, pval, pidx, K, c, seg_len);
    hipLaunchKernelGGL(k_gt_reduce, dim3(G), dim3(64), 0, stream,
                       pval, pidx, gt_best);
    hipLaunchKernelGGL(k_anchor, dim3(NB), dim3(256), 0, stream,
                       gt, meta, gt_best, out_anch, out_bb, out_lab, posc, negc, K, c, G);
    hipLaunchKernelGGL(k_scan, dim3(1), dim3(1024), 0, stream,
                       posc, negc, numbg, NB);
    hipLaunchKernelGGL(k_apply, dim3(NB), dim3(256), 0, stream,
                       out_lab, posc, negc, numbg, K);
}